// Round 2
// baseline (757.638 us; speedup 1.0000x reference)
//
#include <hip/hip_runtime.h>

#define NB 64
#define NC 321
#define ND 512
#define NP 720
#define NPPAD 768

#define BN 128
#define BK 64
#define NPT 6   // p-tiles of 128 over padded 768

typedef __bf16 bf16x8 __attribute__((ext_vector_type(8)));
typedef float f32x4 __attribute__((ext_vector_type(4)));
typedef unsigned short u16x8 __attribute__((ext_vector_type(8)));

typedef __attribute__((address_space(1))) const void* gas_ptr;
typedef __attribute__((address_space(3))) void* las_ptr;
#define GLLD16(gp, lp) __builtin_amdgcn_global_load_lds((gas_ptr)(gp), (las_ptr)(lp), 16, 0, 0)

__device__ __forceinline__ unsigned short f2bf(float f) {
    unsigned int u = __builtin_bit_cast(unsigned int, f);
    return (unsigned short)((u + 0x7FFFu + ((u >> 16) & 1u)) >> 16);
}

// ---------- kernel 1a: x [B,C,D] f32 -> xb [B,C,D] bf16 (pure stream) ----------
__global__ __launch_bounds__(256) void convert_x_kernel(
    const float* __restrict__ x, unsigned short* __restrict__ xb)
{
    // 8 elements per thread; total NB*NC*ND = 10,518,528 = 5136 blocks * 2048
    size_t base = ((size_t)blockIdx.x * 256 + threadIdx.x) * 8;
    f32x4 a = *(const f32x4*)(x + base);
    f32x4 b = *(const f32x4*)(x + base + 4);
    u16x8 v = { f2bf(a[0]), f2bf(a[1]), f2bf(a[2]), f2bf(a[3]),
                f2bf(b[0]), f2bf(b[1]), f2bf(b[2]), f2bf(b[3]) };
    *(u16x8*)(xb + base) = v;
}

// ---------- kernel 1b: W [C,D,P] f32 -> Wt [C,NPPAD,D] bf16 (tiled transpose) ----------
// block: 64d x 64p tile. grid (12 ptiles, 8 dtiles, C)
__global__ __launch_bounds__(256) void convert_W_kernel(
    const float* __restrict__ W, unsigned short* __restrict__ Wt)
{
    const int p0 = blockIdx.x * 64;
    const int d0 = blockIdx.y * 64;
    const int c  = blockIdx.z;
    const int t  = threadIdx.x;

    __shared__ __align__(16) float tile[64 * 65];

    const float* src = W + (size_t)c * (ND * NP);
#pragma unroll
    for (int i = 0; i < 4; ++i) {
        int r   = (t >> 4) + i * 16;      // d offset 0..63
        int col = (t & 15) * 4;           // p offset 0..60
        int p   = p0 + col;
        f32x4 v;
        if (p + 3 < NP) {
            v = *(const f32x4*)(src + (size_t)(d0 + r) * NP + p);
        } else {
#pragma unroll
            for (int j = 0; j < 4; ++j)
                v[j] = (p + j < NP) ? src[(size_t)(d0 + r) * NP + p + j] : 0.f;
        }
        *(f32x4*)(&tile[r * 65 + col]) = v;
    }
    __syncthreads();

#pragma unroll
    for (int i = 0; i < 2; ++i) {
        int task = t + i * 256;
        int pp = task >> 3;    // 0..63
        int dg = task & 7;     // 0..7 (8 d per chunk)
        if (p0 + pp < NP) {
            u16x8 v;
#pragma unroll
            for (int j = 0; j < 8; ++j)
                v[j] = f2bf(tile[(dg * 8 + j) * 65 + pp]);
            *(u16x8*)(Wt + ((size_t)c * NPPAD + p0 + pp) * ND + d0 + dg * 8) = v;
        }
    }
}

// ---------- kernel 2: GEMM, m97 structure ----------
// out[m,c,p] = sum_d xb[m,c,d] * Wt[c,p,d] + bias[c,p]
// block (pt, c): M=64, N=128, BK=64, 256 thr = 4 waves (2m x 2n).
// LDS bf16: A [64 rows x 128B] swizzled, B [128 rows x 128B] swizzled.
// Staging via global_load_lds width 16; swizzle realized by permuting the
// per-lane GLOBAL addresses (LDS side is lane-linear, m104/m108).
__global__ __launch_bounds__(256) void gemm_kernel(
    const unsigned short* __restrict__ xb, const unsigned short* __restrict__ Wt,
    const float* __restrict__ bias, float* __restrict__ out)
{
    const int pt = blockIdx.x;
    const int c  = blockIdx.y;
    const int p0 = pt * BN;

    const int tid  = threadIdx.x;
    const int lane = tid & 63;
    const int wid  = tid >> 6;
    const int lr   = lane & 15;
    const int qd   = lane >> 4;
    const int lrow = lane >> 3;   // 0..7 within staging chunk
    const int g    = lane & 7;    // 16B granule within 128B row

    __shared__ __align__(16) unsigned short lds[(64 + BN) * BK]; // A:[0,4096) B:[4096,12288)

    // staging source pointers: wave w -> A chunks {2w,2w+1}, B chunks {4w..4w+3}
    const unsigned short* a_src[2];
#pragma unroll
    for (int i = 0; i < 2; ++i) {
        int ca = wid * 2 + i;
        int m  = ca * 8 + lrow;
        a_src[i] = xb + (size_t)m * (NC * ND) + (size_t)c * ND + ((g ^ (m & 7)) << 3);
    }
    const unsigned short* b_src[4];
#pragma unroll
    for (int i = 0; i < 4; ++i) {
        int cb = wid * 4 + i;
        int n  = cb * 8 + lrow;
        b_src[i] = Wt + ((size_t)c * NPPAD + p0 + n) * ND + ((g ^ (n & 7)) << 3);
    }
    unsigned short* a_dst[2] = { &lds[(wid * 2 + 0) * 512], &lds[(wid * 2 + 1) * 512] };
    unsigned short* b_dst[4] = { &lds[4096 + (wid * 4 + 0) * 512], &lds[4096 + (wid * 4 + 1) * 512],
                                 &lds[4096 + (wid * 4 + 2) * 512], &lds[4096 + (wid * 4 + 3) * 512] };

    const int mbase = (wid & 1) << 5;
    const int nbase = (wid >> 1) << 6;

    f32x4 acc[2][4];
#pragma unroll
    for (int ms = 0; ms < 2; ++ms)
#pragma unroll
        for (int ns = 0; ns < 4; ++ns)
            acc[ms][ns] = (f32x4){0.f, 0.f, 0.f, 0.f};

    for (int kt = 0; kt < ND / BK; ++kt) {
        if (kt) __syncthreads();

#pragma unroll
        for (int i = 0; i < 2; ++i) GLLD16(a_src[i], a_dst[i]);
#pragma unroll
        for (int i = 0; i < 4; ++i) GLLD16(b_src[i], b_dst[i]);
#pragma unroll
        for (int i = 0; i < 2; ++i) a_src[i] += BK;
#pragma unroll
        for (int i = 0; i < 4; ++i) b_src[i] += BK;

        __syncthreads();

#pragma unroll
        for (int ks = 0; ks < 2; ++ks) {
            const int gk = ks * 4 + qd;
            bf16x8 af[2], bfr[4];
#pragma unroll
            for (int ms = 0; ms < 2; ++ms) {
                int row = mbase + ms * 16 + lr;
                af[ms] = __builtin_bit_cast(bf16x8,
                    *(const u16x8*)(&lds[row * BK + ((gk ^ (row & 7)) << 3)]));
            }
#pragma unroll
            for (int ns = 0; ns < 4; ++ns) {
                int n = nbase + ns * 16 + lr;
                bfr[ns] = __builtin_bit_cast(bf16x8,
                    *(const u16x8*)(&lds[4096 + n * BK + ((gk ^ (n & 7)) << 3)]));
            }
#pragma unroll
            for (int ms = 0; ms < 2; ++ms)
#pragma unroll
                for (int ns = 0; ns < 4; ++ns)
                    acc[ms][ns] = __builtin_amdgcn_mfma_f32_16x16x32_bf16(
                        af[ms], bfr[ns], acc[ms][ns], 0, 0, 0);
        }
    }

    // epilogue: C/D layout col(p)=lane&15, row(m)=(lane>>4)*4+reg
#pragma unroll
    for (int ns = 0; ns < 4; ++ns) {
        int p = p0 + nbase + ns * 16 + lr;
        if (p < NP) {
            float bb = bias[c * NP + p];
#pragma unroll
            for (int ms = 0; ms < 2; ++ms) {
                int row0 = mbase + ms * 16 + qd * 4;
                float* op = out + (size_t)row0 * (NC * NP) + (size_t)c * NP + p;
#pragma unroll
                for (int r = 0; r < 4; ++r)
                    op[(size_t)r * (NC * NP)] = acc[ms][ns][r] + bb;
            }
        }
    }
}

extern "C" void kernel_launch(void* const* d_in, const int* in_sizes, int n_in,
                              void* d_out, int out_size, void* d_ws, size_t ws_size,
                              hipStream_t stream) {
    const float* x  = (const float*)d_in[0];
    const float* W  = (const float*)d_in[1];
    const float* b  = (const float*)d_in[2];
    float* out      = (float*)d_out;

    unsigned short* Wt = (unsigned short*)d_ws;                       // C*NPPAD*ND bf16
    unsigned short* xb = (unsigned short*)((char*)d_ws + (size_t)NC * NPPAD * ND * 2);

    convert_x_kernel<<<dim3(5136), dim3(256), 0, stream>>>(x, xb);
    convert_W_kernel<<<dim3(12, 8, NC), dim3(256), 0, stream>>>(W, Wt);
    gemm_kernel<<<dim3(NPT, NC), dim3(256), 0, stream>>>(xb, Wt, b, out);
}